// Round 10
// baseline (326.648 us; speedup 1.0000x reference)
//
#include <hip/hip_runtime.h>

#define BB 8
#define CC 512
#define LL 2048
#define GG 4
#define CPG 128   // channels per group

typedef _Float16 f16;
typedef _Float16 f16x8 __attribute__((ext_vector_type(8)));
typedef float f32x4 __attribute__((ext_vector_type(4)));

__device__ __forceinline__ void gload_lds16(const f16* g, f16* l)
{
    __builtin_amdgcn_global_load_lds(
        (__attribute__((address_space(1))) void*)g,
        (__attribute__((address_space(3))) void*)l, 16, 0, 0);
}

// ---------------------------------------------------------------------------
// Fused: weight conversion (blocks 0-1023) + GroupNorm partial sums (1024-2047)
// ---------------------------------------------------------------------------
__global__ __launch_bounds__(256) void convert_gn(
    const float* __restrict__ qw, const float* __restrict__ kw,
    const float* __restrict__ vw, const float* __restrict__ pw,
    const float* __restrict__ qb, const float* __restrict__ kb,
    const float* __restrict__ x,
    f16* __restrict__ Wqk, f16* __restrict__ Wv, f16* __restrict__ Wp,
    float* __restrict__ qkb, float2* __restrict__ part)
{
    int bid = blockIdx.x;
    if (bid < 1024) {
        int i = bid * 256 + threadIdx.x;
        if (i < CC * CC) {
            Wqk[i]           = (f16)qw[i];
            Wqk[CC * CC + i] = (f16)kw[i];
            Wv[i]            = (f16)vw[i];
            Wp[i]            = (f16)pw[i];
        }
        if (i < CC) { qkb[i] = qb[i]; qkb[CC + i] = kb[i]; }
    } else {
        int r = bid - 1024;
        int s = r & 31, g = (r >> 5) & 3, b = r >> 7;
        const float4* p = (const float4*)(x + (size_t)b * CC * LL
                                            + (size_t)g * CPG * LL + (size_t)s * 8192);
        float sum = 0.f, sq = 0.f;
        for (int i = threadIdx.x; i < 2048; i += 256) {
            float4 v = p[i];
            sum += v.x + v.y + v.z + v.w;
            sq  += v.x * v.x + v.y * v.y + v.z * v.z + v.w * v.w;
        }
        for (int o = 32; o; o >>= 1) { sum += __shfl_xor(sum, o); sq += __shfl_xor(sq, o); }
        __shared__ float2 red[4];
        int wave = threadIdx.x >> 6, lane = threadIdx.x & 63;
        if (lane == 0) red[wave] = make_float2(sum, sq);
        __syncthreads();
        if (threadIdx.x == 0) {
            float S = red[0].x + red[1].x + red[2].x + red[3].x;
            float Q = red[0].y + red[1].y + red[2].y + red[3].y;
            part[((size_t)b * GG + g) * 32 + s] = make_float2(S, Q);
        }
    }
}

// GroupNorm normalize + affine + TRANSPOSE: x [C,L] fp32 -> xnT [L,C] f16.
// Stats derived in-block from the 32 per-slice partials (gn_finalize folded in).
__global__ __launch_bounds__(256) void gn_norm_t(
    const float* __restrict__ x, const float2* __restrict__ part,
    const float* __restrict__ gw, const float* __restrict__ gb,
    f16* __restrict__ xnT)
{
    __shared__ float t[64][65];
    __shared__ float2 stLds;
    int l0 = blockIdx.x * 64, c0 = blockIdx.y * 64, b = blockIdx.z;
    int tid = threadIdx.x;
    if (tid < 32) {
        float2 p = part[((size_t)b * GG + (c0 >> 7)) * 32 + tid];
        float s = p.x, q = p.y;
        for (int o = 16; o; o >>= 1) { s += __shfl_xor(s, o); q += __shfl_xor(q, o); }
        if (tid == 0) {
            const float invN = 1.0f / (float)(CPG * LL);
            float mean = s * invN;
            float var  = q * invN - mean * mean;
            stLds = make_float2(mean, rsqrtf(var + 1e-6f));
        }
    }
    __syncthreads();
    float2 st = stLds;
    const float* xb = x + (size_t)b * CC * LL;
    for (int i = tid; i < 4096; i += 256) {
        int c = i >> 6, l = i & 63;
        float v = xb[(size_t)(c0 + c) * LL + l0 + l];
        t[c][l] = (v - st.x) * st.y * gw[c0 + c] + gb[c0 + c];
    }
    __syncthreads();
    f16* o = xnT + (size_t)b * LL * CC;
    for (int i = tid; i < 4096; i += 256) {
        int l = i >> 6, c = i & 63;
        o[(size_t)(l0 + l) * CC + c0 + c] = (f16)t[c][l];
    }
}

// ---------------------------------------------------------------------------
// Batched GEMM  C[M,N] = alpha * A[M,K] · B[N,K]^T (+bias)(+resid)
// Tile 128 x (NBT*32), BK=64, 4 waves (2x2), per-wave 64 x (NBT*16).
//   NBT=4: 128x128, 33.5KB LDS -> 4 blocks/CU;  NBT=8: 128x256, 50KB -> 3/CU.
// __launch_bounds__ min-waves/EU raised accordingly (R10: occupancy lever —
// cross-block wave overlap is what hides the per-K-tile barrier drain, m114).
// Staging: global_load_lds w=16, linear LDS dest + inverse-swizzled source.
// Read swizzle: phys=(row*128+col)^((row&7)<<4), measured 0-conflict.
// XCD-aware bijective block swizzle (T1): logical = (hw&7)*(nwg/8) + hw>>3.
// Epilogue modes: BIAS_MODE 0/1(row)/2(col); RESID; SOFTEXP (exp + per-block
// row sums -> rowpart[(bz*M+row)*gridDim.x + bn]); ROWSCALE (reads the 8
// rowparts per row in a prologue, v *= 1/sum).
// ---------------------------------------------------------------------------
template<int NBT, int BIAS_MODE, bool RESID, bool SOFTEXP, bool ROWSCALE, typename OUT_T>
__global__ __launch_bounds__(256, (NBT == 4 ? 4 : 3)) void gemm_bt(
    const f16* __restrict__ A, size_t sA,
    const f16* __restrict__ B, size_t sB,
    OUT_T* __restrict__ Co, size_t sC,
    const float* __restrict__ resid, size_t sR,
    const float* __restrict__ bias,
    float* __restrict__ rowpart,
    int M, int N, int K, int lda, int ldb, int ldc, float alpha)
{
    constexpr int BN = NBT * 32;

    const int tid  = threadIdx.x;
    const int lane = tid & 63;
    const int wave = tid >> 6;
    const int wr = wave >> 1, wc = wave & 1;
    const int l15 = lane & 15, lhi = lane >> 4;

    // XCD-aware bijective swizzle over the flattened grid (nwg % 8 == 0)
    const int GX = gridDim.x, GXY = gridDim.x * gridDim.y;
    const int nwg = GXY * gridDim.z;
    int lin = blockIdx.z * GXY + blockIdx.y * GX + blockIdx.x;
    int logical = (lin & 7) * (nwg >> 3) + (lin >> 3);
    const int bz = logical / GXY;
    int rem = logical - bz * GXY;
    const int bm = rem / GX;
    const int bn = rem - bm * GX;

    A  += (size_t)bz * sA;
    B  += (size_t)bz * sB;
    Co += (size_t)bz * sC;

    __shared__ f16 ldsA[128 * 64];
    __shared__ f16 ldsB[BN * 64];
    __shared__ float rsl[128];

    f32x4 acc[4][NBT] = {};

    if constexpr (ROWSCALE) {
        if (tid < 128) {
            const float* rp = rowpart + ((size_t)bz * M + bm * 128 + tid) * 8;
            float s = 0.f;
#pragma unroll
            for (int k = 0; k < 8; ++k) s += rp[k];
            rsl[tid] = 1.0f / s;
        }
        // first __syncthreads inside the K-loop orders rsl before epilogue use
    }

    // staging source column (elements), inverse-swizzled; constant per lane
    const int srcColE = ((lane & 7) ^ (lane >> 3)) * 8;
    const int rowBase = wave * 8 + (lane >> 3);          // + it*32
    const f16* Ag = A + (size_t)(bm * 128 + rowBase) * lda + srcColE;
    const f16* Bg = B + (size_t)(bn * BN  + rowBase) * ldb + srcColE;

    for (int k0 = 0; k0 < K; k0 += 64) {
#pragma unroll
        for (int it = 0; it < 4; ++it)
            gload_lds16(Ag + (size_t)(it * 32) * lda + k0,
                        (f16*)((char*)ldsA + it * 4096 + wave * 1024));
#pragma unroll
        for (int it = 0; it < NBT; ++it)
            gload_lds16(Bg + (size_t)(it * 32) * ldb + k0,
                        (f16*)((char*)ldsB + it * 4096 + wave * 1024));
        __syncthreads();
#pragma unroll
        for (int kk = 0; kk < 64; kk += 32) {
            const int kb2 = (kk + lhi * 8) * 2;   // byte col of fragment
            f16x8 af[4], bfr[NBT];
#pragma unroll
            for (int m = 0; m < 4; ++m) {
                int row = wr * 64 + m * 16 + l15;
                int phys = ((row * 128 + kb2) ^ ((row & 7) << 4)) >> 1;
                af[m] = *(const f16x8*)(ldsA + phys);
            }
#pragma unroll
            for (int n = 0; n < NBT; ++n) {
                int row = wc * (NBT * 16) + n * 16 + l15;
                int phys = ((row * 128 + kb2) ^ ((row & 7) << 4)) >> 1;
                bfr[n] = *(const f16x8*)(ldsB + phys);
            }
#pragma unroll
            for (int m = 0; m < 4; ++m)
#pragma unroll
                for (int n = 0; n < NBT; ++n)
                    acc[m][n] = __builtin_amdgcn_mfma_f32_16x16x32_f16(
                        af[m], bfr[n], acc[m][n], 0, 0, 0);
        }
        __syncthreads();
    }

    if constexpr (SOFTEXP) {
        // exp epilogue + deterministic per-block row sums (no atomics)
        __shared__ float rs2[2][128];
        float rowacc[16];
#pragma unroll
        for (int i = 0; i < 16; ++i) rowacc[i] = 0.f;
#pragma unroll
        for (int m = 0; m < 4; ++m) {
#pragma unroll
            for (int n = 0; n < NBT; ++n) {
                int col = bn * BN + wc * (NBT * 16) + n * 16 + l15;
#pragma unroll
                for (int r = 0; r < 4; ++r) {
                    int row = bm * 128 + wr * 64 + m * 16 + lhi * 4 + r;
                    float e = __expf(fminf(acc[m][n][r] * alpha, 11.0f));
                    rowacc[m * 4 + r] += e;
                    Co[(size_t)row * ldc + col] = (OUT_T)e;
                }
            }
        }
        // butterfly over l15 group (lanes sharing lhi hold the same rows)
#pragma unroll
        for (int off = 1; off < 16; off <<= 1)
#pragma unroll
            for (int i = 0; i < 16; ++i)
                rowacc[i] += __shfl_xor(rowacc[i], off);
        if (l15 == 0) {
#pragma unroll
            for (int i = 0; i < 16; ++i)
                rs2[wc][wr * 64 + (i >> 2) * 16 + lhi * 4 + (i & 3)] = rowacc[i];
        }
        __syncthreads();
        if (tid < 128) {
            int row = bm * 128 + tid;
            rowpart[((size_t)bz * M + row) * gridDim.x + bn] =
                rs2[0][tid] + rs2[1][tid];
        }
    } else {
#pragma unroll
        for (int m = 0; m < 4; ++m) {
#pragma unroll
            for (int n = 0; n < NBT; ++n) {
                int col = bn * BN + wc * (NBT * 16) + n * 16 + l15;
#pragma unroll
                for (int r = 0; r < 4; ++r) {
                    int row = bm * 128 + wr * 64 + m * 16 + lhi * 4 + r;
                    float v = acc[m][n][r] * alpha;
                    if (BIAS_MODE == 1) v += bias[row];
                    if (BIAS_MODE == 2) v += bias[col];
                    if (ROWSCALE) v *= rsl[row - bm * 128];
                    if (RESID) v += resid[(size_t)bz * sR + (size_t)row * ldc + col];
                    Co[(size_t)row * ldc + col] = (OUT_T)v;
                }
            }
        }
    }
}

// Fallback marker if workspace is too small (distinct absmax signal ~12345)
__global__ void fill_marker(float* out, int n)
{
    int i = blockIdx.x * 256 + threadIdx.x;
    if (i < n) out[i] = 12345.0f;
}

// ---------------------------------------------------------------------------
extern "C" void kernel_launch(void* const* d_in, const int* in_sizes, int n_in,
                              void* d_out, int out_size, void* d_ws, size_t ws_size,
                              hipStream_t stream)
{
    const float* x  = (const float*)d_in[0];
    const float* gw = (const float*)d_in[1];
    const float* gb = (const float*)d_in[2];
    const float* qw = (const float*)d_in[3];
    const float* qb = (const float*)d_in[4];
    const float* kw = (const float*)d_in[5];
    const float* kb = (const float*)d_in[6];
    const float* vw = (const float*)d_in[7];
    const float* vb = (const float*)d_in[8];
    const float* pw = (const float*)d_in[9];
    const float* pb = (const float*)d_in[10];
    float* out = (float*)d_out;

    // workspace layout (bytes)
    char* w = (char*)d_ws;
    float2* part  = (float2*)w;                       //   8 KB
    f16* Wqk  = (f16*)(w + 16384);                    //   1 MB   [1024,512]
    f16* Wv   = Wqk + (size_t)1024 * CC;              // 512 KB   [512,512]
    f16* Wp   = Wv  + (size_t)CC * CC;                // 512 KB
    float* qkb = (float*)(Wp + (size_t)CC * CC);      //   4 KB
    f16* xnT  = (f16*)((char*)qkb + 4096);            // 16 MB    [B][L,C]
    f16* QK   = xnT + (size_t)BB * LL * CC;           // 32 MB    [B][L,1024]
    f16* Vm   = QK  + (size_t)BB * LL * 1024;         // 16 MB    [B][C,L]
    f16* Pm   = Vm  + (size_t)BB * CC * LL;           // 64 MB    [B][L,L]
    float* rowpart = (float*)(Pm + (size_t)BB * LL * LL);  // 512 KB [B*L][8]
    f16* O2   = xnT;  // alias: xnT dead after gemm2  //          [B][L,C]
    size_t need = (size_t)((char*)(rowpart + (size_t)BB * LL * 8) - w);
    if (ws_size < need) {
        fill_marker<<<(out_size + 255) / 256, 256, 0, stream>>>(out, out_size);
        return;
    }

    convert_gn<<<dim3(2048), 256, 0, stream>>>(
        qw, kw, vw, pw, qb, kb, x, Wqk, Wv, Wp, qkb, part);
    gn_norm_t<<<dim3(LL / 64, CC / 64, BB), 256, 0, stream>>>(x, part, gw, gb, xnT);

    // GEMM1: [Q|K]t[l, n] = xnT[l,:] . Wqk[n,:] + qkb[n]     (M=L, N=1024, K=C)
    gemm_bt<8, 2, false, false, false, f16><<<dim3(1024 / 256, LL / 128, BB), 256, 0, stream>>>(
        xnT, (size_t)LL * CC, Wqk, 0, QK, (size_t)LL * 1024, nullptr, 0, qkb,
        nullptr,
        LL, 1024, CC, CC, CC, 1024, 1.0f);

    // GEMM2: V[c, l] = Wv[c,:] . xnT[l,:] + vb[c]            (M=C, N=L, K=C)
    gemm_bt<4, 1, false, false, false, f16><<<dim3(LL / 128, CC / 128, BB), 256, 0, stream>>>(
        Wv, 0, xnT, (size_t)LL * CC, Vm, (size_t)CC * LL, nullptr, 0, vb,
        nullptr,
        CC, LL, CC, CC, CC, LL, 1.0f);

    // GEMM3: P'[i, j] = exp(scale * Qt[i,:] . Kt[j,:]) ; rowpart  (M=L, N=L, K=C)
    gemm_bt<8, 0, false, true, false, f16><<<dim3(LL / 256, LL / 128, BB), 256, 0, stream>>>(
        QK, (size_t)LL * 1024, QK + CC, (size_t)LL * 1024, Pm, (size_t)LL * LL,
        nullptr, 0, nullptr,
        rowpart,
        LL, LL, CC, 1024, 1024, LL, 0.04419417382415922f);

    // GEMM4: O2[i, c] = (P'[i,:] . V[c,:]) / rowsum[i]       (M=L, N=C, K=L)
    gemm_bt<4, 0, false, false, true, f16><<<dim3(CC / 128, LL / 128, BB), 256, 0, stream>>>(
        Pm, (size_t)LL * LL, Vm, (size_t)CC * LL, O2, (size_t)LL * CC,
        nullptr, 0, nullptr,
        rowpart,
        LL, CC, LL, LL, LL, CC, 1.0f);

    // GEMM5: out[c, l] = Wp[c,:] . O2[l,:] + pb[c] + x[c,l]  (M=C, N=L, K=C)
    gemm_bt<4, 1, true, false, false, float><<<dim3(LL / 128, CC / 128, BB), 256, 0, stream>>>(
        Wp, 0, O2, (size_t)LL * CC, out, (size_t)CC * LL, x, (size_t)CC * LL, pb,
        nullptr,
        CC, LL, CC, CC, CC, LL, 1.0f);
}

// Round 11
// 152.996 us; speedup vs baseline: 2.1350x; 2.1350x over previous
//
#include <hip/hip_runtime.h>

#define BB 8
#define CC 512
#define LL 2048
#define GG 4
#define CPG 128   // channels per group

typedef _Float16 f16;
typedef _Float16 f16x4 __attribute__((ext_vector_type(4)));
typedef _Float16 f16x8 __attribute__((ext_vector_type(8)));
typedef float f32x4 __attribute__((ext_vector_type(4)));

__device__ __forceinline__ void gload_lds16(const f16* g, f16* l)
{
    __builtin_amdgcn_global_load_lds(
        (__attribute__((address_space(1))) void*)g,
        (__attribute__((address_space(3))) void*)l, 16, 0, 0);
}

// ---------------------------------------------------------------------------
// Fused: weight conversion, vectorized float4->f16x4 (blocks 0-255)
//        + GroupNorm partial sums (blocks 256-1279)
// ---------------------------------------------------------------------------
__global__ __launch_bounds__(256) void convert_gn(
    const float* __restrict__ qw, const float* __restrict__ kw,
    const float* __restrict__ vw, const float* __restrict__ pw,
    const float* __restrict__ qb, const float* __restrict__ kb,
    const float* __restrict__ x,
    f16* __restrict__ Wqk, f16* __restrict__ Wv, f16* __restrict__ Wp,
    float* __restrict__ qkb, float2* __restrict__ part)
{
    int bid = blockIdx.x;
    if (bid < 256) {
        int j = bid * 256 + threadIdx.x;
        int i = j * 4;                       // covers CC*CC exactly
        float4 q4 = *(const float4*)(qw + i);
        float4 k4 = *(const float4*)(kw + i);
        float4 v4 = *(const float4*)(vw + i);
        float4 p4 = *(const float4*)(pw + i);
        f16x4 o;
        o[0] = (f16)q4.x; o[1] = (f16)q4.y; o[2] = (f16)q4.z; o[3] = (f16)q4.w;
        *(f16x4*)(Wqk + i) = o;
        o[0] = (f16)k4.x; o[1] = (f16)k4.y; o[2] = (f16)k4.z; o[3] = (f16)k4.w;
        *(f16x4*)(Wqk + CC * CC + i) = o;
        o[0] = (f16)v4.x; o[1] = (f16)v4.y; o[2] = (f16)v4.z; o[3] = (f16)v4.w;
        *(f16x4*)(Wv + i) = o;
        o[0] = (f16)p4.x; o[1] = (f16)p4.y; o[2] = (f16)p4.z; o[3] = (f16)p4.w;
        *(f16x4*)(Wp + i) = o;
        if (j < CC) { qkb[j] = qb[j]; qkb[CC + j] = kb[j]; }
    } else {
        int r = bid - 256;
        int s = r & 31, g = (r >> 5) & 3, b = r >> 7;
        const float4* p = (const float4*)(x + (size_t)b * CC * LL
                                            + (size_t)g * CPG * LL + (size_t)s * 8192);
        float sum = 0.f, sq = 0.f;
        for (int i = threadIdx.x; i < 2048; i += 256) {
            float4 v = p[i];
            sum += v.x + v.y + v.z + v.w;
            sq  += v.x * v.x + v.y * v.y + v.z * v.z + v.w * v.w;
        }
        for (int o = 32; o; o >>= 1) { sum += __shfl_xor(sum, o); sq += __shfl_xor(sq, o); }
        __shared__ float2 red[4];
        int wave = threadIdx.x >> 6, lane = threadIdx.x & 63;
        if (lane == 0) red[wave] = make_float2(sum, sq);
        __syncthreads();
        if (threadIdx.x == 0) {
            float S = red[0].x + red[1].x + red[2].x + red[3].x;
            float Q = red[0].y + red[1].y + red[2].y + red[3].y;
            part[((size_t)b * GG + g) * 32 + s] = make_float2(S, Q);
        }
    }
}

// GroupNorm normalize + affine + TRANSPOSE: x [C,L] fp32 -> xnT [L,C] f16.
// Stats derived in-block from the 32 per-slice partials. Vectorized paths:
// x read float4 x4 (16B/lane), xnT write f16x8 (16B/lane, 8-row x 64-col
// coalesced wave segments); LDS re-read is 2-way bank-aliased (free, m136).
__global__ __launch_bounds__(256) void gn_norm_t(
    const float* __restrict__ x, const float2* __restrict__ part,
    const float* __restrict__ gw, const float* __restrict__ gb,
    f16* __restrict__ xnT)
{
    __shared__ float t[64][65];
    __shared__ float2 stLds;
    int l0 = blockIdx.x * 64, c0 = blockIdx.y * 64, b = blockIdx.z;
    int tid = threadIdx.x;
    if (tid < 32) {
        float2 p = part[((size_t)b * GG + (c0 >> 7)) * 32 + tid];
        float s = p.x, q = p.y;
        for (int o = 16; o; o >>= 1) { s += __shfl_xor(s, o); q += __shfl_xor(q, o); }
        if (tid == 0) {
            const float invN = 1.0f / (float)(CPG * LL);
            float mean = s * invN;
            float var  = q * invN - mean * mean;
            stLds = make_float2(mean, rsqrtf(var + 1e-6f));
        }
    }
    __syncthreads();
    float2 st = stLds;
    const float* xb = x + (size_t)b * CC * LL;
    {
        int c = tid >> 2, lb = (tid & 3) * 16;
        float g = gw[c0 + c], b2 = gb[c0 + c];
        const float4* src = (const float4*)(xb + (size_t)(c0 + c) * LL + l0 + lb);
#pragma unroll
        for (int q = 0; q < 4; ++q) {
            float4 v = src[q];
            int l = lb + q * 4;
            t[c][l + 0] = (v.x - st.x) * st.y * g + b2;
            t[c][l + 1] = (v.y - st.x) * st.y * g + b2;
            t[c][l + 2] = (v.z - st.x) * st.y * g + b2;
            t[c][l + 3] = (v.w - st.x) * st.y * g + b2;
        }
    }
    __syncthreads();
    f16* o = xnT + (size_t)b * LL * CC;
    {
        int c8 = (tid & 7) * 8;
#pragma unroll
        for (int h = 0; h < 2; ++h) {
            int l = (tid >> 3) + h * 32;
            f16x8 v;
#pragma unroll
            for (int u = 0; u < 8; ++u) v[u] = (f16)t[c8 + u][l];
            *(f16x8*)(o + (size_t)(l0 + l) * CC + c0 + c8) = v;
        }
    }
}

// ---------------------------------------------------------------------------
// Batched GEMM  C[M,N] = alpha * A[M,K] · B[N,K]^T (+bias)(+resid)
// Tile 128 x (NBT*32), BK=64, 4 waves (2x2), per-wave 64 x (NBT*16).
//   NBT=4: 128x128, 33.5KB LDS;  NBT=8: 128x256, 50KB LDS.
// __launch_bounds__(256,2) — R10 lesson: forcing >=3 blocks/CU caps VGPR
// below the accumulator footprint and spills acc to scratch (WRITE_SIZE 5x).
// Staging: global_load_lds w=16, linear LDS dest + inverse-swizzled source.
// Read swizzle: phys=(row*128+col)^((row&7)<<4), measured 0-conflict.
// XCD-aware bijective block swizzle (T1): logical = (hw&7)*(nwg/8) + hw>>3.
// Epilogue modes: BIAS_MODE 0/1(row)/2(col); RESID; SOFTEXP (exp + per-block
// row sums -> rowpart[(bz*M+row)*gridDim.x + bn]); ROWSCALE (reads the 8
// rowparts per row in a prologue, v *= 1/sum).
// ---------------------------------------------------------------------------
template<int NBT, int BIAS_MODE, bool RESID, bool SOFTEXP, bool ROWSCALE, typename OUT_T>
__global__ __launch_bounds__(256, 2) void gemm_bt(
    const f16* __restrict__ A, size_t sA,
    const f16* __restrict__ B, size_t sB,
    OUT_T* __restrict__ Co, size_t sC,
    const float* __restrict__ resid, size_t sR,
    const float* __restrict__ bias,
    float* __restrict__ rowpart,
    int M, int N, int K, int lda, int ldb, int ldc, float alpha)
{
    constexpr int BN = NBT * 32;

    const int tid  = threadIdx.x;
    const int lane = tid & 63;
    const int wave = tid >> 6;
    const int wr = wave >> 1, wc = wave & 1;
    const int l15 = lane & 15, lhi = lane >> 4;

    // XCD-aware bijective swizzle over the flattened grid (nwg % 8 == 0)
    const int GX = gridDim.x, GXY = gridDim.x * gridDim.y;
    const int nwg = GXY * gridDim.z;
    int lin = blockIdx.z * GXY + blockIdx.y * GX + blockIdx.x;
    int logical = (lin & 7) * (nwg >> 3) + (lin >> 3);
    const int bz = logical / GXY;
    int rem = logical - bz * GXY;
    const int bm = rem / GX;
    const int bn = rem - bm * GX;

    A  += (size_t)bz * sA;
    B  += (size_t)bz * sB;
    Co += (size_t)bz * sC;

    __shared__ f16 ldsA[128 * 64];
    __shared__ f16 ldsB[BN * 64];
    __shared__ float rsl[128];

    f32x4 acc[4][NBT] = {};

    if constexpr (ROWSCALE) {
        if (tid < 128) {
            const float* rp = rowpart + ((size_t)bz * M + bm * 128 + tid) * 8;
            float s = 0.f;
#pragma unroll
            for (int k = 0; k < 8; ++k) s += rp[k];
            rsl[tid] = 1.0f / s;
        }
        // first __syncthreads inside the K-loop orders rsl before epilogue use
    }

    // staging source column (elements), inverse-swizzled; constant per lane
    const int srcColE = ((lane & 7) ^ (lane >> 3)) * 8;
    const int rowBase = wave * 8 + (lane >> 3);          // + it*32
    const f16* Ag = A + (size_t)(bm * 128 + rowBase) * lda + srcColE;
    const f16* Bg = B + (size_t)(bn * BN  + rowBase) * ldb + srcColE;

    for (int k0 = 0; k0 < K; k0 += 64) {
#pragma unroll
        for (int it = 0; it < 4; ++it)
            gload_lds16(Ag + (size_t)(it * 32) * lda + k0,
                        (f16*)((char*)ldsA + it * 4096 + wave * 1024));
#pragma unroll
        for (int it = 0; it < NBT; ++it)
            gload_lds16(Bg + (size_t)(it * 32) * ldb + k0,
                        (f16*)((char*)ldsB + it * 4096 + wave * 1024));
        __syncthreads();
#pragma unroll
        for (int kk = 0; kk < 64; kk += 32) {
            const int kb2 = (kk + lhi * 8) * 2;   // byte col of fragment
            f16x8 af[4], bfr[NBT];
#pragma unroll
            for (int m = 0; m < 4; ++m) {
                int row = wr * 64 + m * 16 + l15;
                int phys = ((row * 128 + kb2) ^ ((row & 7) << 4)) >> 1;
                af[m] = *(const f16x8*)(ldsA + phys);
            }
#pragma unroll
            for (int n = 0; n < NBT; ++n) {
                int row = wc * (NBT * 16) + n * 16 + l15;
                int phys = ((row * 128 + kb2) ^ ((row & 7) << 4)) >> 1;
                bfr[n] = *(const f16x8*)(ldsB + phys);
            }
#pragma unroll
            for (int m = 0; m < 4; ++m)
#pragma unroll
                for (int n = 0; n < NBT; ++n)
                    acc[m][n] = __builtin_amdgcn_mfma_f32_16x16x32_f16(
                        af[m], bfr[n], acc[m][n], 0, 0, 0);
        }
        __syncthreads();
    }

    if constexpr (SOFTEXP) {
        // exp epilogue + deterministic per-block row sums (no atomics)
        __shared__ float rs2[2][128];
        float rowacc[16];
#pragma unroll
        for (int i = 0; i < 16; ++i) rowacc[i] = 0.f;
#pragma unroll
        for (int m = 0; m < 4; ++m) {
#pragma unroll
            for (int n = 0; n < NBT; ++n) {
                int col = bn * BN + wc * (NBT * 16) + n * 16 + l15;
#pragma unroll
                for (int r = 0; r < 4; ++r) {
                    int row = bm * 128 + wr * 64 + m * 16 + lhi * 4 + r;
                    float e = __expf(fminf(acc[m][n][r] * alpha, 11.0f));
                    rowacc[m * 4 + r] += e;
                    Co[(size_t)row * ldc + col] = (OUT_T)e;
                }
            }
        }
        // butterfly over l15 group (lanes sharing lhi hold the same rows)
#pragma unroll
        for (int off = 1; off < 16; off <<= 1)
#pragma unroll
            for (int i = 0; i < 16; ++i)
                rowacc[i] += __shfl_xor(rowacc[i], off);
        if (l15 == 0) {
#pragma unroll
            for (int i = 0; i < 16; ++i)
                rs2[wc][wr * 64 + (i >> 2) * 16 + lhi * 4 + (i & 3)] = rowacc[i];
        }
        __syncthreads();
        if (tid < 128) {
            int row = bm * 128 + tid;
            rowpart[((size_t)bz * M + row) * gridDim.x + bn] =
                rs2[0][tid] + rs2[1][tid];
        }
    } else {
#pragma unroll
        for (int m = 0; m < 4; ++m) {
#pragma unroll
            for (int n = 0; n < NBT; ++n) {
                int col = bn * BN + wc * (NBT * 16) + n * 16 + l15;
#pragma unroll
                for (int r = 0; r < 4; ++r) {
                    int row = bm * 128 + wr * 64 + m * 16 + lhi * 4 + r;
                    float v = acc[m][n][r] * alpha;
                    if (BIAS_MODE == 1) v += bias[row];
                    if (BIAS_MODE == 2) v += bias[col];
                    if (ROWSCALE) v *= rsl[row - bm * 128];
                    if (RESID) v += resid[(size_t)bz * sR + (size_t)row * ldc + col];
                    Co[(size_t)row * ldc + col] = (OUT_T)v;
                }
            }
        }
    }
}

// Fallback marker if workspace is too small (distinct absmax signal ~12345)
__global__ void fill_marker(float* out, int n)
{
    int i = blockIdx.x * 256 + threadIdx.x;
    if (i < n) out[i] = 12345.0f;
}

// ---------------------------------------------------------------------------
extern "C" void kernel_launch(void* const* d_in, const int* in_sizes, int n_in,
                              void* d_out, int out_size, void* d_ws, size_t ws_size,
                              hipStream_t stream)
{
    const float* x  = (const float*)d_in[0];
    const float* gw = (const float*)d_in[1];
    const float* gb = (const float*)d_in[2];
    const float* qw = (const float*)d_in[3];
    const float* qb = (const float*)d_in[4];
    const float* kw = (const float*)d_in[5];
    const float* kb = (const float*)d_in[6];
    const float* vw = (const float*)d_in[7];
    const float* vb = (const float*)d_in[8];
    const float* pw = (const float*)d_in[9];
    const float* pb = (const float*)d_in[10];
    float* out = (float*)d_out;

    // workspace layout (bytes)
    char* w = (char*)d_ws;
    float2* part  = (float2*)w;                       //   8 KB
    f16* Wqk  = (f16*)(w + 16384);                    //   1 MB   [1024,512]
    f16* Wv   = Wqk + (size_t)1024 * CC;              // 512 KB   [512,512]
    f16* Wp   = Wv  + (size_t)CC * CC;                // 512 KB
    float* qkb = (float*)(Wp + (size_t)CC * CC);      //   4 KB
    f16* xnT  = (f16*)((char*)qkb + 4096);            // 16 MB    [B][L,C]
    f16* QK   = xnT + (size_t)BB * LL * CC;           // 32 MB    [B][L,1024]
    f16* Vm   = QK  + (size_t)BB * LL * 1024;         // 16 MB    [B][C,L]
    f16* Pm   = Vm  + (size_t)BB * CC * LL;           // 64 MB    [B][L,L]
    float* rowpart = (float*)(Pm + (size_t)BB * LL * LL);  // 512 KB [B*L][8]
    f16* O2   = xnT;  // alias: xnT dead after gemm2  //          [B][L,C]
    size_t need = (size_t)((char*)(rowpart + (size_t)BB * LL * 8) - w);
    if (ws_size < need) {
        fill_marker<<<(out_size + 255) / 256, 256, 0, stream>>>(out, out_size);
        return;
    }

    convert_gn<<<dim3(1280), 256, 0, stream>>>(
        qw, kw, vw, pw, qb, kb, x, Wqk, Wv, Wp, qkb, part);
    gn_norm_t<<<dim3(LL / 64, CC / 64, BB), 256, 0, stream>>>(x, part, gw, gb, xnT);

    // GEMM1: [Q|K]t[l, n] = xnT[l,:] . Wqk[n,:] + qkb[n]     (M=L, N=1024, K=C)
    gemm_bt<8, 2, false, false, false, f16><<<dim3(1024 / 256, LL / 128, BB), 256, 0, stream>>>(
        xnT, (size_t)LL * CC, Wqk, 0, QK, (size_t)LL * 1024, nullptr, 0, qkb,
        nullptr,
        LL, 1024, CC, CC, CC, 1024, 1.0f);

    // GEMM2: V[c, l] = Wv[c,:] . xnT[l,:] + vb[c]            (M=C, N=L, K=C)
    gemm_bt<4, 1, false, false, false, f16><<<dim3(LL / 128, CC / 128, BB), 256, 0, stream>>>(
        Wv, 0, xnT, (size_t)LL * CC, Vm, (size_t)CC * LL, nullptr, 0, vb,
        nullptr,
        CC, LL, CC, CC, CC, LL, 1.0f);

    // GEMM3: P'[i, j] = exp(scale * Qt[i,:] . Kt[j,:]) ; rowpart  (M=L, N=L, K=C)
    gemm_bt<8, 0, false, true, false, f16><<<dim3(LL / 256, LL / 128, BB), 256, 0, stream>>>(
        QK, (size_t)LL * 1024, QK + CC, (size_t)LL * 1024, Pm, (size_t)LL * LL,
        nullptr, 0, nullptr,
        rowpart,
        LL, LL, CC, 1024, 1024, LL, 0.04419417382415922f);

    // GEMM4: O2[i, c] = (P'[i,:] . V[c,:]) / rowsum[i]       (M=L, N=C, K=L)
    gemm_bt<4, 0, false, false, true, f16><<<dim3(CC / 128, LL / 128, BB), 256, 0, stream>>>(
        Pm, (size_t)LL * LL, Vm, (size_t)CC * LL, O2, (size_t)LL * CC,
        nullptr, 0, nullptr,
        rowpart,
        LL, CC, LL, LL, LL, CC, 1.0f);

    // GEMM5: out[c, l] = Wp[c,:] . O2[l,:] + pb[c] + x[c,l]  (M=C, N=L, K=C)
    gemm_bt<4, 1, true, false, false, float><<<dim3(LL / 128, CC / 128, BB), 256, 0, stream>>>(
        Wp, 0, O2, (size_t)LL * CC, out, (size_t)CC * LL, x, (size_t)CC * LL, pb,
        nullptr,
        CC, LL, CC, CC, CC, LL, 1.0f);
}